// Round 12
// baseline (196.750 us; speedup 1.0000x reference)
//
#include <hip/hip_runtime.h>
#include <cstdint>
#include <cstddef>

// Problem constants
#define B_    8
#define C_    256
#define H_    64
#define W_    64
#define A_    4
#define NH_   8
#define DH_   32
#define L_    1024
#define NPAIR 32
#define QKVN  768

typedef __bf16 bf16;
typedef __bf16 bf16x8 __attribute__((ext_vector_type(8)));
typedef __bf16 bf16x4 __attribute__((ext_vector_type(4)));
typedef float  f32x4  __attribute__((ext_vector_type(4)));

// dh^-0.5 * log2(e): folded into Q at projection time
#define QSCALE 0.25506866729736328f

__device__ inline f32x4 mfma16(bf16x8 a, bf16x8 b, f32x4 c) {
    return __builtin_amdgcn_mfma_f32_16x16x32_bf16(a, b, c, 0, 0, 0);
}
__device__ inline bf16x8 ld8(const bf16* p) { return *(const bf16x8*)p; }

// async global->LDS, 16B per lane; LDS dest = wave-uniform base + lane*16
__device__ inline void stage16(const bf16* g, bf16* l) {
    __builtin_amdgcn_global_load_lds(
        (const __attribute__((address_space(1))) void*)g,
        (__attribute__((address_space(3))) void*)l, 16, 0, 0);
}

// ---------------------------------------------------------------------------
// K0: fused  (a) x[B,C,H,W] f32 -> xa[pair,l,c] bf16   [blocks 0..1023]
//            (b) W_in/W_out f32 -> bf16 convert        [blocks 1024..2047]
// ---------------------------------------------------------------------------
#define NW4 (786432 / 4)
#define NO4 (262144 / 4)
__global__ __launch_bounds__(256) void k_split(const float* __restrict__ x,
                                               bf16* __restrict__ xa,
                                               const float* __restrict__ Win,
                                               const float* __restrict__ Wout,
                                               bf16* __restrict__ Winb,
                                               bf16* __restrict__ Woutb) {
    __shared__ float lds[32][257];
    int bid = blockIdx.x;
    int t = threadIdx.x;
    if (bid >= NPAIR * 32) {
        int tid = (bid - NPAIR * 32) * 256 + t;
        if (tid < NW4) {
            float4 v = ((const float4*)Win)[tid];
            bf16x4 ov = {(bf16)v.x, (bf16)v.y, (bf16)v.z, (bf16)v.w};
            ((bf16x4*)Winb)[tid] = ov;
        } else if (tid < NW4 + NO4) {
            int t2 = tid - NW4;
            float4 v = ((const float4*)Wout)[t2];
            bf16x4 ov = {(bf16)v.x, (bf16)v.y, (bf16)v.z, (bf16)v.w};
            ((bf16x4*)Woutb)[t2] = ov;
        }
        return;
    }
    int pair = bid >> 5, p = bid & 31;
    int b = pair >> 2, a = pair & 3, i = a >> 1, j = a & 1;
    int q = t & 31, csub = t >> 5;
    const float* xb = x + (size_t)b * C_ * H_ * W_ + (size_t)(i * 32 + p) * W_ + j * 32;
    for (int r = 0; r < 32; ++r) {
        int c = r * 8 + csub;
        lds[q][c] = xb[(size_t)c * H_ * W_ + q];
    }
    __syncthreads();
    bf16* xr = xa + ((size_t)pair * L_ + (size_t)p * 32) * C_;
    for (int r = 0; r < 32; ++r) {
        xr[(size_t)r * C_ + t] = (bf16)lds[r][t];
    }
}

// ---------------------------------------------------------------------------
// K1: in-projection GEMM (tile 128x128, BK=64, 4 waves 2x2, 64x64/wave).
// R9 stage/compute overlap + R7 coalesced epilogue (both verified wins).
// grid: 32 pair x 8 mt x 6 nt = 1536
// ---------------------------------------------------------------------------
__global__ __launch_bounds__(256) void k_qkv(const bf16* __restrict__ xa,
                                             const bf16* __restrict__ Win,
                                             const float* __restrict__ bin,
                                             bf16* __restrict__ qk,
                                             bf16* __restrict__ vT) {
    __shared__ __align__(16) char smem[32768];
    bf16* lA = (bf16*)smem;              // 128*64*2 = 16384
    bf16* lB = (bf16*)(smem + 16384);    // 128*64*2 = 16384
    int bid = blockIdx.x;
    int nt = bid % 6, mt = (bid / 6) & 7, pair = bid / 48;
    int a = pair & 3;
    int t = threadIdx.x, w = t >> 6, lane = t & 63;
    int wm = w >> 1, wn = w & 1;
    int quad = lane >> 4, l16 = lane & 15;
    int m0 = mt * 128, n0 = nt * 128;
    int r8 = lane >> 3, pc = lane & 7, jj = pc ^ r8;
    const bf16* ga = xa + (size_t)pair * L_ * C_ + (size_t)(m0 + w * 32 + r8) * C_ + jj * 8;
    const bf16* gb = Win + (size_t)a * QKVN * C_ + (size_t)(n0 + w * 32 + r8) * C_ + jj * 8;
    f32x4 acc[4][4];
#pragma unroll
    for (int fm = 0; fm < 4; ++fm)
#pragma unroll
        for (int fn = 0; fn < 4; ++fn) acc[fm][fn] = (f32x4){0.f, 0.f, 0.f, 0.f};
    // prologue: stage k0
#pragma unroll
    for (int i = 0; i < 4; ++i) {
        stage16(ga + (size_t)(i * 8) * C_, lA + (w * 32 + i * 8) * 64);
        stage16(gb + (size_t)(i * 8) * C_, lB + (w * 32 + i * 8) * 64);
    }
    for (int k0 = 0; k0 < C_; k0 += 64) {
        __syncthreads();  // stage for this k-step complete (vmcnt drained at barrier)
        // pull ALL fragments for this k-step into registers
        bf16x8 am[2][4], bn[2][4];
#pragma unroll
        for (int ks = 0; ks < 2; ++ks) {
            int p = (ks * 4 + quad) ^ (l16 & 7);
#pragma unroll
            for (int f = 0; f < 4; ++f) {
                am[ks][f] = *(const bf16x8*)&lA[(wm * 64 + f * 16 + l16) * 64 + p * 8];
                bn[ks][f] = *(const bf16x8*)&lB[(wn * 64 + f * 16 + l16) * 64 + p * 8];
            }
        }
        __syncthreads();  // all waves consumed LDS (ds_reads drained at barrier)
        // stage next k-step; latency hides under the MFMA burst below
        if (k0 + 64 < C_) {
            int kn = k0 + 64;
#pragma unroll
            for (int i = 0; i < 4; ++i) {
                stage16(ga + (size_t)(i * 8) * C_ + kn, lA + (w * 32 + i * 8) * 64);
                stage16(gb + (size_t)(i * 8) * C_ + kn, lB + (w * 32 + i * 8) * 64);
            }
        }
#pragma unroll
        for (int ks = 0; ks < 2; ++ks)
#pragma unroll
            for (int fm = 0; fm < 4; ++fm)
#pragma unroll
                for (int fn = 0; fn < 4; ++fn)
                    acc[fm][fn] = mfma16(am[ks][fm], bn[ks][fn], acc[fm][fn]);
    }
    int colbase = n0 + wn * 64;
    int mb = m0 + wm * 64;
    __syncthreads();  // all waves done with lA/lB -> reuse as per-wave slabs
    bf16* slab = (bf16*)smem + w * 2304;  // [32][72] bf16 per wave (4608B)
    float bias[4];
#pragma unroll
    for (int fn = 0; fn < 4; ++fn) bias[fn] = bin[a * QKVN + colbase + fn * 16 + l16];
    int sr = lane >> 3, seg = lane & 7;
    if (colbase < 512) {
        float sc = (colbase < 256) ? QSCALE : 1.0f;
        bf16* ob = qk + (size_t)pair * L_ * 512;
#pragma unroll
        for (int pass = 0; pass < 2; ++pass) {
#pragma unroll
            for (int k = 0; k < 2; ++k) {
                int fm = pass * 2 + k;
#pragma unroll
                for (int fn = 0; fn < 4; ++fn)
#pragma unroll
                    for (int r = 0; r < 4; ++r)
                        slab[(k * 16 + quad * 4 + r) * 72 + fn * 16 + l16] =
                            (bf16)((acc[fm][fn][r] + bias[fn]) * sc);
            }
#pragma unroll
            for (int rr = 0; rr < 4; ++rr) {
                int row = rr * 8 + sr;
                bf16x8 v = *(const bf16x8*)&slab[row * 72 + seg * 8];
                *(bf16x8*)&ob[(size_t)(mb + pass * 32 + row) * 512 + colbase + seg * 8] = v;
            }
        }
    } else {
        bf16* vb = vT + (size_t)pair * C_ * L_;
        int e00 = colbase - 512;
#pragma unroll
        for (int pass = 0; pass < 2; ++pass) {
#pragma unroll
            for (int k = 0; k < 2; ++k) {
                int fn = pass * 2 + k;
#pragma unroll
                for (int fm = 0; fm < 4; ++fm) {
                    bf16x4 pk = {(bf16)(acc[fm][fn][0] + bias[fn]), (bf16)(acc[fm][fn][1] + bias[fn]),
                                 (bf16)(acc[fm][fn][2] + bias[fn]), (bf16)(acc[fm][fn][3] + bias[fn])};
                    *(bf16x4*)&slab[(k * 16 + l16) * 72 + fm * 16 + quad * 4] = pk;
                }
            }
#pragma unroll
            for (int rr = 0; rr < 4; ++rr) {
                int el = rr * 8 + sr;
                bf16x8 v = *(const bf16x8*)&slab[el * 72 + seg * 8];
                *(bf16x8*)&vb[(size_t)(e00 + pass * 32 + el) * L_ + mb + seg * 8] = v;
            }
        }
    }
}

// ---------------------------------------------------------------------------
// K2: attention. R6-EXACT (verified 67.2-68.9us, VGPR 56, 8 waves/SIMD).
// Sits ON the 64-VGPR occupancy cliff; no register-adding trades.
// grid: pair = bid&31, head = (bid>>5)&7, qb = bid>>8 (0..7). 2048 blocks.
// ---------------------------------------------------------------------------
__global__ __launch_bounds__(256) void k_attn(const bf16* __restrict__ qk,
                                              const bf16* __restrict__ vT,
                                              bf16* __restrict__ o) {
    __shared__ __align__(16) bf16 pl[4][1024];     // per-wave 16x64 P, swizzled (8 KiB)
    __shared__ __align__(16) bf16 klds[4 * 512];   // 4 KiB
    __shared__ __align__(16) bf16 vlds[4 * 512];   // 4 KiB
    int bid = blockIdx.x;
    int pair = bid & 31, rest = bid >> 5;
    int head = rest & 7, qb = rest >> 3;  // qb 0..7
    int t = threadIdx.x, w = t >> 6, lane = t & 63, quad = lane >> 4, l16 = lane & 15;
    const bf16* qbp = qk + (size_t)pair * L_ * 512;
    const bf16* kg = qbp + (size_t)(l16 * 4 + w) * 512 + 256 + head * DH_ + quad * 8;
    const bf16* vg = vT + ((size_t)pair * C_ + head * DH_ + (w & 1) * 16 + l16) * L_
                        + (w >> 1) * 32 + quad * 8;
    bf16* kdst = &klds[w * 512];
    bf16* vdst = &vlds[w * 512];
    int qbase = qb * 128 + w * 32;
    bf16x8 qf[2];
    f32x4 acc0[2], acc1[2], l4[2];
#pragma unroll
    for (int f = 0; f < 2; ++f) {
        qf[f] = ld8(qbp + (size_t)(qbase + f * 16 + l16) * 512 + head * DH_ + quad * 8);
        acc0[f] = (f32x4){0.f, 0.f, 0.f, 0.f};
        acc1[f] = (f32x4){0.f, 0.f, 0.f, 0.f};
        l4[f]   = (f32x4){0.f, 0.f, 0.f, 0.f};
    }
    // prologue: stage tile 0
    stage16(kg, kdst);
    stage16(vg, vdst);
    __syncthreads();  // vmcnt drained -> tile 0 in LDS

    for (int kv0 = 0; kv0 < L_; kv0 += 64) {
        // pull tile's K/V fragments into regs (lane-linear -> conflict-free)
        bf16x8 kf[4], vf[4];
#pragma unroll
        for (int i = 0; i < 4; ++i) {
            kf[i] = ld8(&klds[(i * 64 + lane) * 8]);
            vf[i] = ld8(&vlds[(i * 64 + lane) * 8]);
        }
        __syncthreads();  // all waves consumed LDS K/V
        // stage tile t+1 (wraps harmlessly on last iter); latency hides under compute
        int kvn = (kv0 + 64) & (L_ - 1);
        stage16(kg + (size_t)kvn * 512, kdst);
        stage16(vg + kvn, vdst);
#pragma unroll
        for (int f = 0; f < 2; ++f) {
            f32x4 s[4];
#pragma unroll
            for (int kb = 0; kb < 4; ++kb) s[kb] = mfma16(qf[f], kf[kb], (f32x4){0.f, 0.f, 0.f, 0.f});
            char* pw = (char*)&pl[w][0];
#pragma unroll
            for (int r = 0; r < 4; ++r) {
                float p0 = __builtin_amdgcn_exp2f(s[0][r]);
                float p1 = __builtin_amdgcn_exp2f(s[1][r]);
                float p2 = __builtin_amdgcn_exp2f(s[2][r]);
                float p3 = __builtin_amdgcn_exp2f(s[3][r]);
                l4[f][r] += (p0 + p1) + (p2 + p3);
                bf16x4 pv = {(bf16)p0, (bf16)p1, (bf16)p2, (bf16)p3};
                int row = quad * 4 + r;
                int wo = (row * 128 + l16 * 8) ^ ((row & 7) << 4);
                *(bf16x4*)(pw + wo) = pv;
            }
#pragma unroll
            for (int ks = 0; ks < 2; ++ks) {
                int ro = (l16 * 128 + ks * 64 + quad * 16) ^ ((l16 & 7) << 4);
                bf16x8 pf = *(const bf16x8*)(pw + ro);
                acc0[f] = mfma16(pf, vf[ks * 2 + 0], acc0[f]);
                acc1[f] = mfma16(pf, vf[ks * 2 + 1], acc1[f]);
            }
        }
        __syncthreads();  // vmcnt drained -> tile t+1 ready in LDS
    }
    bf16* orow = o + (size_t)pair * L_ * C_ + head * DH_;
#pragma unroll
    for (int f = 0; f < 2; ++f) {
#pragma unroll
        for (int r = 0; r < 4; ++r) {
            float s1 = l4[f][r];
#pragma unroll
            for (int off = 1; off < 16; off <<= 1) s1 += __shfl_xor(s1, off);
            float inv = 1.f / s1;
            int row = qbase + f * 16 + quad * 4 + r;
            orow[(size_t)row * C_ + l16]      = (bf16)(acc0[f][r] * inv);
            orow[(size_t)row * C_ + 16 + l16] = (bf16)(acc1[f][r] * inv);
        }
    }
}

// ---------------------------------------------------------------------------
// K3: y = LayerNorm(o @ W_out[a]^T + b_out[a] + xa) * gamma + beta
//     FUSED with merge: writes out[B,C,H,W] f32 directly.
// R12: R8 geometry (tile 64x256, grid 512 = 2 blocks/CU -- the verified-best
// config; R11's 32-row tile doubled B-staging and regressed) + R9 overlap
// ordering in the k-loop (barrier -> frags to regs -> barrier -> stage next
// -> MFMA). The +40 VGPR of holding both ks-halves is FREE here: LDS (41KB)
// caps at 2 blocks/CU = 8 waves/CU regardless, so no occupancy cliff.
// grid: 32 pair x 16 mt = 512
// ---------------------------------------------------------------------------
__global__ __launch_bounds__(256) void k_out(const bf16* __restrict__ o,
                                             const bf16* __restrict__ Wout,
                                             const float* __restrict__ bout,
                                             const bf16* __restrict__ xa,
                                             const float* __restrict__ gamma,
                                             const float* __restrict__ beta,
                                             float* __restrict__ out) {
    __shared__ __align__(16) char smem[40960];
    bf16* lA = (bf16*)smem;            // 64*64*2 = 8192
    bf16* lB = (bf16*)(smem + 8192);   // 256*64*2 = 32768
    float* tr = (float*)smem;          // 32*258*4 = 33024, reused post-GEMM
    __shared__ float red[2][2][32][2];
    int bid = blockIdx.x;
    int mt = bid & 15, pair = bid >> 4;
    int a = pair & 3;
    int t = threadIdx.x, w = t >> 6, lane = t & 63;
    int wm = w >> 1, wn = w & 1;
    int quad = lane >> 4, l16 = lane & 15;
    int m0 = mt * 64;
    int r8 = lane >> 3, pc = lane & 7, jj = pc ^ r8;
    const bf16* ga = o + (size_t)pair * L_ * C_ + (size_t)(m0 + w * 16 + r8) * C_ + jj * 8;
    const bf16* gb = Wout + (size_t)a * C_ * C_ + (size_t)(w * 64 + r8) * C_ + jj * 8;
    f32x4 acc[2][8];
#pragma unroll
    for (int fm = 0; fm < 2; ++fm)
#pragma unroll
        for (int fn = 0; fn < 8; ++fn) acc[fm][fn] = (f32x4){0.f, 0.f, 0.f, 0.f};
    // prologue: stage k0
#pragma unroll
    for (int i = 0; i < 2; ++i)
        stage16(ga + (size_t)(i * 8) * C_, lA + (w * 16 + i * 8) * 64);
#pragma unroll
    for (int i = 0; i < 8; ++i)
        stage16(gb + (size_t)(i * 8) * C_, lB + (w * 64 + i * 8) * 64);
    for (int k0 = 0; k0 < C_; k0 += 64) {
        __syncthreads();  // stage for this k-step complete
        bf16x8 am[2][2], bn[2][8];
#pragma unroll
        for (int ks = 0; ks < 2; ++ks) {
            int p = (ks * 4 + quad) ^ (l16 & 7);
#pragma unroll
            for (int f = 0; f < 2; ++f)
                am[ks][f] = *(const bf16x8*)&lA[(wm * 32 + f * 16 + l16) * 64 + p * 8];
#pragma unroll
            for (int f = 0; f < 8; ++f)
                bn[ks][f] = *(const bf16x8*)&lB[(wn * 128 + f * 16 + l16) * 64 + p * 8];
        }
        __syncthreads();  // all waves consumed LDS
        // stage next k-step; latency hides under the MFMA burst below
        if (k0 + 64 < C_) {
            int kn = k0 + 64;
#pragma unroll
            for (int i = 0; i < 2; ++i)
                stage16(ga + (size_t)(i * 8) * C_ + kn, lA + (w * 16 + i * 8) * 64);
#pragma unroll
            for (int i = 0; i < 8; ++i)
                stage16(gb + (size_t)(i * 8) * C_ + kn, lB + (w * 64 + i * 8) * 64);
        }
#pragma unroll
        for (int ks = 0; ks < 2; ++ks)
#pragma unroll
            for (int fm = 0; fm < 2; ++fm)
#pragma unroll
                for (int fn = 0; fn < 8; ++fn)
                    acc[fm][fn] = mfma16(am[ks][fm], bn[ks][fn], acc[fm][fn]);
    }
    // bias + residual into acc; hoist gamma/beta
    const bf16* xb = xa + ((size_t)pair * L_ + m0 + wm * 32) * C_;
    float g8[8], be8[8];
#pragma unroll
    for (int fn = 0; fn < 8; ++fn) {
        int col = wn * 128 + fn * 16 + l16;
        float bias = bout[a * C_ + col];
        g8[fn] = gamma[col];
        be8[fn] = beta[col];
#pragma unroll
        for (int fm = 0; fm < 2; ++fm)
#pragma unroll
            for (int r = 0; r < 4; ++r)
                acc[fm][fn][r] += bias + (float)xb[(size_t)(fm * 16 + quad * 4 + r) * C_ + col];
    }
    // per-wave partial row sums -> LDS
#pragma unroll
    for (int fm = 0; fm < 2; ++fm) {
#pragma unroll
        for (int r = 0; r < 4; ++r) {
            float s1 = 0.f, s2 = 0.f;
#pragma unroll
            for (int fn = 0; fn < 8; ++fn) {
                float v = acc[fm][fn][r];
                s1 += v; s2 += v * v;
            }
#pragma unroll
            for (int off = 1; off < 16; off <<= 1) {
                s1 += __shfl_xor(s1, off);
                s2 += __shfl_xor(s2, off);
            }
            if (l16 == 0) {
                int rl = fm * 16 + quad * 4 + r;
                red[wm][wn][rl][0] = s1;
                red[wm][wn][rl][1] = s2;
            }
        }
    }
    __syncthreads();  // red ready; all GEMM LDS reads done -> tr may reuse smem
    // normalize in place
#pragma unroll
    for (int fm = 0; fm < 2; ++fm) {
#pragma unroll
        for (int r = 0; r < 4; ++r) {
            int rl = fm * 16 + quad * 4 + r;
            float t1 = red[wm][0][rl][0] + red[wm][1][rl][0];
            float t2 = red[wm][0][rl][1] + red[wm][1][rl][1];
            float mu = t1 * (1.f / 256.f);
            float var = t2 * (1.f / 256.f) - mu * mu;
            float rstd = rsqrtf(var + 1e-5f);
#pragma unroll
            for (int fn = 0; fn < 8; ++fn)
                acc[fm][fn][r] = (acc[fm][fn][r] - mu) * rstd * g8[fn] + be8[fn];
        }
    }
    // fused merge: 2 chunks of 32 l-rows; each chunk = one h row of out
    int b = pair >> 2, i = (a >> 1), j = a & 1;
    int q = t & 31, csub = t >> 5;
    float* ob = out + (size_t)b * C_ * H_ * W_ + (size_t)(i * 32 + (m0 >> 5)) * W_ + j * 32;
#pragma unroll
    for (int ch = 0; ch < 2; ++ch) {
        __syncthreads();  // previous chunk's reads done before overwriting tr
        if (wm == ch) {
#pragma unroll
            for (int fm = 0; fm < 2; ++fm) {
                int rb = fm * 16 + quad * 4;
#pragma unroll
                for (int r = 0; r < 4; ++r)
#pragma unroll
                    for (int fn = 0; fn < 8; ++fn)
                        tr[(rb + r) * 258 + wn * 128 + fn * 16 + l16] = acc[fm][fn][r];
            }
        }
        __syncthreads();  // slab ready
#pragma unroll
        for (int r32 = 0; r32 < 32; ++r32) {
            int c = r32 * 8 + csub;
            ob[(size_t)c * (H_ * W_) + (size_t)ch * W_ + q] = tr[q * 258 + c];
        }
    }
}

// ---------------------------------------------------------------------------
extern "C" void kernel_launch(void* const* d_in, const int* in_sizes, int n_in,
                              void* d_out, int out_size, void* d_ws, size_t ws_size,
                              hipStream_t stream) {
    (void)in_sizes; (void)n_in; (void)out_size; (void)ws_size;
    const float* x     = (const float*)d_in[0];
    const float* Win   = (const float*)d_in[1];
    const float* bin   = (const float*)d_in[2];
    const float* Wout  = (const float*)d_in[3];
    const float* bout  = (const float*)d_in[4];
    const float* gamma = (const float*)d_in[5];
    const float* beta  = (const float*)d_in[6];
    float* out = (float*)d_out;

    char* ws = (char*)d_ws;
    bf16* xa    = (bf16*)ws;                           // 16 MiB
    bf16* qk    = (bf16*)(ws + ((size_t)16 << 20));    // 32 MiB  [pair][L][512]
    bf16* vT    = (bf16*)(ws + ((size_t)48 << 20));    // 16 MiB  [pair][256][1024]
    bf16* o     = (bf16*)(ws + ((size_t)64 << 20));    // 16 MiB
    bf16* Winb  = (bf16*)(ws + ((size_t)80 << 20));    // 1.5 MiB
    bf16* Woutb = (bf16*)(ws + ((size_t)82 << 20));    // 0.5 MiB

    k_split<<<NPAIR * 32 + 1024, 256, 0, stream>>>(x, xa, Win, Wout, Winb, Woutb);
    k_qkv<<<NPAIR * 8 * 6, 256, 0, stream>>>(xa, Winb, bin, qk, vT);
    k_attn<<<NPAIR * NH_ * 8, 256, 0, stream>>>(qk, vT, o);
    k_out<<<NPAIR * 16, 256, 0, stream>>>(o, Woutb, bout, xa, gamma, beta, out);
}

// Round 13
// 191.570 us; speedup vs baseline: 1.0270x; 1.0270x over previous
//
#include <hip/hip_runtime.h>
#include <cstdint>
#include <cstddef>

// Problem constants
#define B_    8
#define C_    256
#define H_    64
#define W_    64
#define A_    4
#define NH_   8
#define DH_   32
#define L_    1024
#define NPAIR 32
#define QKVN  768

typedef __bf16 bf16;
typedef __bf16 bf16x8 __attribute__((ext_vector_type(8)));
typedef __bf16 bf16x4 __attribute__((ext_vector_type(4)));
typedef float  f32x4  __attribute__((ext_vector_type(4)));

// dh^-0.5 * log2(e): folded into Q at projection time
#define QSCALE 0.25506866729736328f

__device__ inline f32x4 mfma16(bf16x8 a, bf16x8 b, f32x4 c) {
    return __builtin_amdgcn_mfma_f32_16x16x32_bf16(a, b, c, 0, 0, 0);
}
__device__ inline bf16x8 ld8(const bf16* p) { return *(const bf16x8*)p; }

// async global->LDS, 16B per lane; LDS dest = wave-uniform base + lane*16
__device__ inline void stage16(const bf16* g, bf16* l) {
    __builtin_amdgcn_global_load_lds(
        (const __attribute__((address_space(1))) void*)g,
        (__attribute__((address_space(3))) void*)l, 16, 0, 0);
}

// ---------------------------------------------------------------------------
// K0: fused  (a) x[B,C,H,W] f32 -> xa[pair,l,c] bf16   [blocks 0..1023]
//            (b) W_in/W_out f32 -> bf16 convert        [blocks 1024..2047]
// ---------------------------------------------------------------------------
#define NW4 (786432 / 4)
#define NO4 (262144 / 4)
__global__ __launch_bounds__(256) void k_split(const float* __restrict__ x,
                                               bf16* __restrict__ xa,
                                               const float* __restrict__ Win,
                                               const float* __restrict__ Wout,
                                               bf16* __restrict__ Winb,
                                               bf16* __restrict__ Woutb) {
    __shared__ float lds[32][257];
    int bid = blockIdx.x;
    int t = threadIdx.x;
    if (bid >= NPAIR * 32) {
        int tid = (bid - NPAIR * 32) * 256 + t;
        if (tid < NW4) {
            float4 v = ((const float4*)Win)[tid];
            bf16x4 ov = {(bf16)v.x, (bf16)v.y, (bf16)v.z, (bf16)v.w};
            ((bf16x4*)Winb)[tid] = ov;
        } else if (tid < NW4 + NO4) {
            int t2 = tid - NW4;
            float4 v = ((const float4*)Wout)[t2];
            bf16x4 ov = {(bf16)v.x, (bf16)v.y, (bf16)v.z, (bf16)v.w};
            ((bf16x4*)Woutb)[t2] = ov;
        }
        return;
    }
    int pair = bid >> 5, p = bid & 31;
    int b = pair >> 2, a = pair & 3, i = a >> 1, j = a & 1;
    int q = t & 31, csub = t >> 5;
    const float* xb = x + (size_t)b * C_ * H_ * W_ + (size_t)(i * 32 + p) * W_ + j * 32;
    for (int r = 0; r < 32; ++r) {
        int c = r * 8 + csub;
        lds[q][c] = xb[(size_t)c * H_ * W_ + q];
    }
    __syncthreads();
    bf16* xr = xa + ((size_t)pair * L_ + (size_t)p * 32) * C_;
    for (int r = 0; r < 32; ++r) {
        xr[(size_t)r * C_ + t] = (bf16)lds[r][t];
    }
}

// ---------------------------------------------------------------------------
// K1: in-projection GEMM (tile 128x128, BK=64, 4 waves 2x2, 64x64/wave).
// R9 stage/compute overlap + R7 coalesced epilogue (both verified wins).
// grid: 32 pair x 8 mt x 6 nt = 1536
// ---------------------------------------------------------------------------
__global__ __launch_bounds__(256) void k_qkv(const bf16* __restrict__ xa,
                                             const bf16* __restrict__ Win,
                                             const float* __restrict__ bin,
                                             bf16* __restrict__ qk,
                                             bf16* __restrict__ vT) {
    __shared__ __align__(16) char smem[32768];
    bf16* lA = (bf16*)smem;              // 128*64*2 = 16384
    bf16* lB = (bf16*)(smem + 16384);    // 128*64*2 = 16384
    int bid = blockIdx.x;
    int nt = bid % 6, mt = (bid / 6) & 7, pair = bid / 48;
    int a = pair & 3;
    int t = threadIdx.x, w = t >> 6, lane = t & 63;
    int wm = w >> 1, wn = w & 1;
    int quad = lane >> 4, l16 = lane & 15;
    int m0 = mt * 128, n0 = nt * 128;
    int r8 = lane >> 3, pc = lane & 7, jj = pc ^ r8;
    const bf16* ga = xa + (size_t)pair * L_ * C_ + (size_t)(m0 + w * 32 + r8) * C_ + jj * 8;
    const bf16* gb = Win + (size_t)a * QKVN * C_ + (size_t)(n0 + w * 32 + r8) * C_ + jj * 8;
    f32x4 acc[4][4];
#pragma unroll
    for (int fm = 0; fm < 4; ++fm)
#pragma unroll
        for (int fn = 0; fn < 4; ++fn) acc[fm][fn] = (f32x4){0.f, 0.f, 0.f, 0.f};
    // prologue: stage k0
#pragma unroll
    for (int i = 0; i < 4; ++i) {
        stage16(ga + (size_t)(i * 8) * C_, lA + (w * 32 + i * 8) * 64);
        stage16(gb + (size_t)(i * 8) * C_, lB + (w * 32 + i * 8) * 64);
    }
    for (int k0 = 0; k0 < C_; k0 += 64) {
        __syncthreads();  // stage for this k-step complete (vmcnt drained at barrier)
        // pull ALL fragments for this k-step into registers
        bf16x8 am[2][4], bn[2][4];
#pragma unroll
        for (int ks = 0; ks < 2; ++ks) {
            int p = (ks * 4 + quad) ^ (l16 & 7);
#pragma unroll
            for (int f = 0; f < 4; ++f) {
                am[ks][f] = *(const bf16x8*)&lA[(wm * 64 + f * 16 + l16) * 64 + p * 8];
                bn[ks][f] = *(const bf16x8*)&lB[(wn * 64 + f * 16 + l16) * 64 + p * 8];
            }
        }
        __syncthreads();  // all waves consumed LDS (ds_reads drained at barrier)
        // stage next k-step; latency hides under the MFMA burst below
        if (k0 + 64 < C_) {
            int kn = k0 + 64;
#pragma unroll
            for (int i = 0; i < 4; ++i) {
                stage16(ga + (size_t)(i * 8) * C_ + kn, lA + (w * 32 + i * 8) * 64);
                stage16(gb + (size_t)(i * 8) * C_ + kn, lB + (w * 32 + i * 8) * 64);
            }
        }
#pragma unroll
        for (int ks = 0; ks < 2; ++ks)
#pragma unroll
            for (int fm = 0; fm < 4; ++fm)
#pragma unroll
                for (int fn = 0; fn < 4; ++fn)
                    acc[fm][fn] = mfma16(am[ks][fm], bn[ks][fn], acc[fm][fn]);
    }
    int colbase = n0 + wn * 64;
    int mb = m0 + wm * 64;
    __syncthreads();  // all waves done with lA/lB -> reuse as per-wave slabs
    bf16* slab = (bf16*)smem + w * 2304;  // [32][72] bf16 per wave (4608B)
    float bias[4];
#pragma unroll
    for (int fn = 0; fn < 4; ++fn) bias[fn] = bin[a * QKVN + colbase + fn * 16 + l16];
    int sr = lane >> 3, seg = lane & 7;
    if (colbase < 512) {
        float sc = (colbase < 256) ? QSCALE : 1.0f;
        bf16* ob = qk + (size_t)pair * L_ * 512;
#pragma unroll
        for (int pass = 0; pass < 2; ++pass) {
#pragma unroll
            for (int k = 0; k < 2; ++k) {
                int fm = pass * 2 + k;
#pragma unroll
                for (int fn = 0; fn < 4; ++fn)
#pragma unroll
                    for (int r = 0; r < 4; ++r)
                        slab[(k * 16 + quad * 4 + r) * 72 + fn * 16 + l16] =
                            (bf16)((acc[fm][fn][r] + bias[fn]) * sc);
            }
#pragma unroll
            for (int rr = 0; rr < 4; ++rr) {
                int row = rr * 8 + sr;
                bf16x8 v = *(const bf16x8*)&slab[row * 72 + seg * 8];
                *(bf16x8*)&ob[(size_t)(mb + pass * 32 + row) * 512 + colbase + seg * 8] = v;
            }
        }
    } else {
        bf16* vb = vT + (size_t)pair * C_ * L_;
        int e00 = colbase - 512;
#pragma unroll
        for (int pass = 0; pass < 2; ++pass) {
#pragma unroll
            for (int k = 0; k < 2; ++k) {
                int fn = pass * 2 + k;
#pragma unroll
                for (int fm = 0; fm < 4; ++fm) {
                    bf16x4 pk = {(bf16)(acc[fm][fn][0] + bias[fn]), (bf16)(acc[fm][fn][1] + bias[fn]),
                                 (bf16)(acc[fm][fn][2] + bias[fn]), (bf16)(acc[fm][fn][3] + bias[fn])};
                    *(bf16x4*)&slab[(k * 16 + l16) * 72 + fm * 16 + quad * 4] = pk;
                }
            }
#pragma unroll
            for (int rr = 0; rr < 4; ++rr) {
                int el = rr * 8 + sr;
                bf16x8 v = *(const bf16x8*)&slab[el * 72 + seg * 8];
                *(bf16x8*)&vb[(size_t)(e00 + pass * 32 + el) * L_ + mb + seg * 8] = v;
            }
        }
    }
}

// ---------------------------------------------------------------------------
// K2: attention. R6-EXACT (verified 66.8-68.9us band, VGPR 56, 8 waves/SIMD).
// Sits ON the 64-VGPR occupancy cliff; no register-adding trades.
// grid: pair = bid&31, head = (bid>>5)&7, qb = bid>>8 (0..7). 2048 blocks.
// ---------------------------------------------------------------------------
__global__ __launch_bounds__(256) void k_attn(const bf16* __restrict__ qk,
                                              const bf16* __restrict__ vT,
                                              bf16* __restrict__ o) {
    __shared__ __align__(16) bf16 pl[4][1024];     // per-wave 16x64 P, swizzled (8 KiB)
    __shared__ __align__(16) bf16 klds[4 * 512];   // 4 KiB
    __shared__ __align__(16) bf16 vlds[4 * 512];   // 4 KiB
    int bid = blockIdx.x;
    int pair = bid & 31, rest = bid >> 5;
    int head = rest & 7, qb = rest >> 3;  // qb 0..7
    int t = threadIdx.x, w = t >> 6, lane = t & 63, quad = lane >> 4, l16 = lane & 15;
    const bf16* qbp = qk + (size_t)pair * L_ * 512;
    const bf16* kg = qbp + (size_t)(l16 * 4 + w) * 512 + 256 + head * DH_ + quad * 8;
    const bf16* vg = vT + ((size_t)pair * C_ + head * DH_ + (w & 1) * 16 + l16) * L_
                        + (w >> 1) * 32 + quad * 8;
    bf16* kdst = &klds[w * 512];
    bf16* vdst = &vlds[w * 512];
    int qbase = qb * 128 + w * 32;
    bf16x8 qf[2];
    f32x4 acc0[2], acc1[2], l4[2];
#pragma unroll
    for (int f = 0; f < 2; ++f) {
        qf[f] = ld8(qbp + (size_t)(qbase + f * 16 + l16) * 512 + head * DH_ + quad * 8);
        acc0[f] = (f32x4){0.f, 0.f, 0.f, 0.f};
        acc1[f] = (f32x4){0.f, 0.f, 0.f, 0.f};
        l4[f]   = (f32x4){0.f, 0.f, 0.f, 0.f};
    }
    // prologue: stage tile 0
    stage16(kg, kdst);
    stage16(vg, vdst);
    __syncthreads();  // vmcnt drained -> tile 0 in LDS

    for (int kv0 = 0; kv0 < L_; kv0 += 64) {
        // pull tile's K/V fragments into regs (lane-linear -> conflict-free)
        bf16x8 kf[4], vf[4];
#pragma unroll
        for (int i = 0; i < 4; ++i) {
            kf[i] = ld8(&klds[(i * 64 + lane) * 8]);
            vf[i] = ld8(&vlds[(i * 64 + lane) * 8]);
        }
        __syncthreads();  // all waves consumed LDS K/V
        // stage tile t+1 (wraps harmlessly on last iter); latency hides under compute
        int kvn = (kv0 + 64) & (L_ - 1);
        stage16(kg + (size_t)kvn * 512, kdst);
        stage16(vg + kvn, vdst);
#pragma unroll
        for (int f = 0; f < 2; ++f) {
            f32x4 s[4];
#pragma unroll
            for (int kb = 0; kb < 4; ++kb) s[kb] = mfma16(qf[f], kf[kb], (f32x4){0.f, 0.f, 0.f, 0.f});
            char* pw = (char*)&pl[w][0];
#pragma unroll
            for (int r = 0; r < 4; ++r) {
                float p0 = __builtin_amdgcn_exp2f(s[0][r]);
                float p1 = __builtin_amdgcn_exp2f(s[1][r]);
                float p2 = __builtin_amdgcn_exp2f(s[2][r]);
                float p3 = __builtin_amdgcn_exp2f(s[3][r]);
                l4[f][r] += (p0 + p1) + (p2 + p3);
                bf16x4 pv = {(bf16)p0, (bf16)p1, (bf16)p2, (bf16)p3};
                int row = quad * 4 + r;
                int wo = (row * 128 + l16 * 8) ^ ((row & 7) << 4);
                *(bf16x4*)(pw + wo) = pv;
            }
#pragma unroll
            for (int ks = 0; ks < 2; ++ks) {
                int ro = (l16 * 128 + ks * 64 + quad * 16) ^ ((l16 & 7) << 4);
                bf16x8 pf = *(const bf16x8*)(pw + ro);
                acc0[f] = mfma16(pf, vf[ks * 2 + 0], acc0[f]);
                acc1[f] = mfma16(pf, vf[ks * 2 + 1], acc1[f]);
            }
        }
        __syncthreads();  // vmcnt drained -> tile t+1 ready in LDS
    }
    bf16* orow = o + (size_t)pair * L_ * C_ + head * DH_;
#pragma unroll
    for (int f = 0; f < 2; ++f) {
#pragma unroll
        for (int r = 0; r < 4; ++r) {
            float s1 = l4[f][r];
#pragma unroll
            for (int off = 1; off < 16; off <<= 1) s1 += __shfl_xor(s1, off);
            float inv = 1.f / s1;
            int row = qbase + f * 16 + quad * 4 + r;
            orow[(size_t)row * C_ + l16]      = (bf16)(acc0[f][r] * inv);
            orow[(size_t)row * C_ + 16 + l16] = (bf16)(acc1[f][r] * inv);
        }
    }
}

// ---------------------------------------------------------------------------
// K3: y = LayerNorm(o @ W_out[a]^T + b_out[a] + xa) * gamma + beta
//     FUSED with merge: writes out[B,C,H,W] f32 directly.
// R8-EXACT (the verified-best k_out; inside the 193.9us R9 run). Tile
// 64x256, grid 512 = 2 blocks/CU, simple two-barrier staged K-loop (R12's
// overlap variant regressed ~5us: 10-instr stage burst + ~40 extra frag
// VGPRs with no occupancy headroom to gain). Merge: 2 chunks of 32 l-rows.
// grid: 32 pair x 16 mt = 512
// ---------------------------------------------------------------------------
__global__ __launch_bounds__(256) void k_out(const bf16* __restrict__ o,
                                             const bf16* __restrict__ Wout,
                                             const float* __restrict__ bout,
                                             const bf16* __restrict__ xa,
                                             const float* __restrict__ gamma,
                                             const float* __restrict__ beta,
                                             float* __restrict__ out) {
    __shared__ __align__(16) char smem[40960];
    bf16* lA = (bf16*)smem;            // 64*64*2 = 8192
    bf16* lB = (bf16*)(smem + 8192);   // 256*64*2 = 32768
    float* tr = (float*)smem;          // 32*258*4 = 33024, reused post-GEMM
    __shared__ float red[2][2][32][2];
    int bid = blockIdx.x;
    int mt = bid & 15, pair = bid >> 4;
    int a = pair & 3;
    int t = threadIdx.x, w = t >> 6, lane = t & 63;
    int wm = w >> 1, wn = w & 1;
    int quad = lane >> 4, l16 = lane & 15;
    int m0 = mt * 64;
    int r8 = lane >> 3, pc = lane & 7, jj = pc ^ r8;
    const bf16* ga = o + (size_t)pair * L_ * C_ + (size_t)(m0 + w * 16 + r8) * C_ + jj * 8;
    const bf16* gb = Wout + (size_t)a * C_ * C_ + (size_t)(w * 64 + r8) * C_ + jj * 8;
    f32x4 acc[2][8];
#pragma unroll
    for (int fm = 0; fm < 2; ++fm)
#pragma unroll
        for (int fn = 0; fn < 8; ++fn) acc[fm][fn] = (f32x4){0.f, 0.f, 0.f, 0.f};
    for (int k0 = 0; k0 < C_; k0 += 64) {
        __syncthreads();
#pragma unroll
        for (int i = 0; i < 2; ++i)
            stage16(ga + (size_t)(i * 8) * C_ + k0, lA + (w * 16 + i * 8) * 64);
#pragma unroll
        for (int i = 0; i < 8; ++i)
            stage16(gb + (size_t)(i * 8) * C_ + k0, lB + (w * 64 + i * 8) * 64);
        __syncthreads();
#pragma unroll
        for (int ks = 0; ks < 2; ++ks) {
            int p = (ks * 4 + quad) ^ (l16 & 7);
            bf16x8 am[2], bn[8];
#pragma unroll
            for (int f = 0; f < 2; ++f)
                am[f] = *(const bf16x8*)&lA[(wm * 32 + f * 16 + l16) * 64 + p * 8];
#pragma unroll
            for (int f = 0; f < 8; ++f)
                bn[f] = *(const bf16x8*)&lB[(wn * 128 + f * 16 + l16) * 64 + p * 8];
#pragma unroll
            for (int fm = 0; fm < 2; ++fm)
#pragma unroll
                for (int fn = 0; fn < 8; ++fn)
                    acc[fm][fn] = mfma16(am[fm], bn[fn], acc[fm][fn]);
        }
    }
    // bias + residual into acc; hoist gamma/beta
    const bf16* xb = xa + ((size_t)pair * L_ + m0 + wm * 32) * C_;
    float g8[8], be8[8];
#pragma unroll
    for (int fn = 0; fn < 8; ++fn) {
        int col = wn * 128 + fn * 16 + l16;
        float bias = bout[a * C_ + col];
        g8[fn] = gamma[col];
        be8[fn] = beta[col];
#pragma unroll
        for (int fm = 0; fm < 2; ++fm)
#pragma unroll
            for (int r = 0; r < 4; ++r)
                acc[fm][fn][r] += bias + (float)xb[(size_t)(fm * 16 + quad * 4 + r) * C_ + col];
    }
    // per-wave partial row sums -> LDS
#pragma unroll
    for (int fm = 0; fm < 2; ++fm) {
#pragma unroll
        for (int r = 0; r < 4; ++r) {
            float s1 = 0.f, s2 = 0.f;
#pragma unroll
            for (int fn = 0; fn < 8; ++fn) {
                float v = acc[fm][fn][r];
                s1 += v; s2 += v * v;
            }
#pragma unroll
            for (int off = 1; off < 16; off <<= 1) {
                s1 += __shfl_xor(s1, off);
                s2 += __shfl_xor(s2, off);
            }
            if (l16 == 0) {
                int rl = fm * 16 + quad * 4 + r;
                red[wm][wn][rl][0] = s1;
                red[wm][wn][rl][1] = s2;
            }
        }
    }
    __syncthreads();  // red ready; all MFMA LDS reads done -> tr may reuse smem
    // normalize in place
#pragma unroll
    for (int fm = 0; fm < 2; ++fm) {
#pragma unroll
        for (int r = 0; r < 4; ++r) {
            int rl = fm * 16 + quad * 4 + r;
            float t1 = red[wm][0][rl][0] + red[wm][1][rl][0];
            float t2 = red[wm][0][rl][1] + red[wm][1][rl][1];
            float mu = t1 * (1.f / 256.f);
            float var = t2 * (1.f / 256.f) - mu * mu;
            float rstd = rsqrtf(var + 1e-5f);
#pragma unroll
            for (int fn = 0; fn < 8; ++fn)
                acc[fm][fn][r] = (acc[fm][fn][r] - mu) * rstd * g8[fn] + be8[fn];
        }
    }
    // fused merge: 2 chunks of 32 l-rows; each chunk = one h row of out
    int b = pair >> 2, i = (a >> 1), j = a & 1;
    int q = t & 31, csub = t >> 5;
    float* ob = out + (size_t)b * C_ * H_ * W_ + (size_t)(i * 32 + (m0 >> 5)) * W_ + j * 32;
#pragma unroll
    for (int ch = 0; ch < 2; ++ch) {
        __syncthreads();  // previous chunk's reads done before overwriting tr
        if (wm == ch) {
#pragma unroll
            for (int fm = 0; fm < 2; ++fm) {
                int rb = fm * 16 + quad * 4;
#pragma unroll
                for (int r = 0; r < 4; ++r)
#pragma unroll
                    for (int fn = 0; fn < 8; ++fn)
                        tr[(rb + r) * 258 + wn * 128 + fn * 16 + l16] = acc[fm][fn][r];
            }
        }
        __syncthreads();  // slab ready
#pragma unroll
        for (int r32 = 0; r32 < 32; ++r32) {
            int c = r32 * 8 + csub;
            ob[(size_t)c * (H_ * W_) + (size_t)ch * W_ + q] = tr[q * 258 + c];
        }
    }
}

// ---------------------------------------------------------------------------
extern "C" void kernel_launch(void* const* d_in, const int* in_sizes, int n_in,
                              void* d_out, int out_size, void* d_ws, size_t ws_size,
                              hipStream_t stream) {
    (void)in_sizes; (void)n_in; (void)out_size; (void)ws_size;
    const float* x     = (const float*)d_in[0];
    const float* Win   = (const float*)d_in[1];
    const float* bin   = (const float*)d_in[2];
    const float* Wout  = (const float*)d_in[3];
    const float* bout  = (const float*)d_in[4];
    const float* gamma = (const float*)d_in[5];
    const float* beta  = (const float*)d_in[6];
    float* out = (float*)d_out;

    char* ws = (char*)d_ws;
    bf16* xa    = (bf16*)ws;                           // 16 MiB
    bf16* qk    = (bf16*)(ws + ((size_t)16 << 20));    // 32 MiB  [pair][L][512]
    bf16* vT    = (bf16*)(ws + ((size_t)48 << 20));    // 16 MiB  [pair][256][1024]
    bf16* o     = (bf16*)(ws + ((size_t)64 << 20));    // 16 MiB
    bf16* Winb  = (bf16*)(ws + ((size_t)80 << 20));    // 1.5 MiB
    bf16* Woutb = (bf16*)(ws + ((size_t)82 << 20));    // 0.5 MiB

    k_split<<<NPAIR * 32 + 1024, 256, 0, stream>>>(x, xa, Win, Wout, Winb, Woutb);
    k_qkv<<<NPAIR * 8 * 6, 256, 0, stream>>>(xa, Winb, bin, qk, vT);
    k_attn<<<NPAIR * NH_ * 8, 256, 0, stream>>>(qk, vT, o);
    k_out<<<NPAIR * 16, 256, 0, stream>>>(o, Woutb, bout, xa, gamma, beta, out);
}